// Round 4
// baseline (243.761 us; speedup 1.0000x reference)
//
#include <hip/hip_runtime.h>
#include <hip/hip_bf16.h>

typedef unsigned short u16;
typedef __attribute__((ext_vector_type(4))) float f32x4;
typedef __attribute__((ext_vector_type(8))) short short8;

#define BN_EPS 1e-5f

__device__ __forceinline__ u16 f2b(float x) {
  union { float f; unsigned int u; } v; v.f = x;
  unsigned int r = (v.u + 0x7FFFu + ((v.u >> 16) & 1u)) >> 16;
  return (u16)r;
}
__device__ __forceinline__ float b2f(u16 u) {
  union { unsigned int u; float f; } v; v.u = ((unsigned int)u) << 16;
  return v.f;
}
__device__ __forceinline__ float asf(unsigned u) {
  union { unsigned u; float f; } v; v.u = u; return v.f;
}

// ---------------------------------------------------------------------------
// prep: all dependency-free data marshalling in one launch.
//  blk <  4096          : f2 [B][256][2048] f32 -> f2t [B][2048][256] bf16
//  blk <  4480          : w1 -> w1b blocked bf16
//  blk <  4736          : w2 -> w2b blocked bf16
//  blk == 4736/4737     : BN fold -> al/bt
//  blk <  4802          : xyz2 -> c4 planar streams [b][4][2048] (x,y,z,|c|^2)
//  blk <  8898          : f1 [B][128][8192] f32 -> xb kt 8..11 blocked bf16
//                         (identical f2b rounding as the old knn phase 3)
// ---------------------------------------------------------------------------
__global__ void prep_kernel(
    const float* __restrict__ f2, u16* __restrict__ f2t,
    const float* __restrict__ w1, const float* __restrict__ b1,
    const float* __restrict__ g1, const float* __restrict__ be1,
    const float* __restrict__ m1, const float* __restrict__ v1,
    const float* __restrict__ w2, const float* __restrict__ b2,
    const float* __restrict__ g2, const float* __restrict__ be2,
    const float* __restrict__ m2, const float* __restrict__ v2,
    const float* __restrict__ xyz2, const float* __restrict__ f1,
    u16* __restrict__ w1b, u16* __restrict__ w2b,
    float* __restrict__ al1, float* __restrict__ bt1,
    float* __restrict__ al2, float* __restrict__ bt2,
    float* __restrict__ c4, u16* __restrict__ xb) {
  __shared__ float tile[32][33];
  __shared__ float tile2[32 * 65];
  int t = threadIdx.x;
  int blk = blockIdx.x;
  if (blk < 4096) {
    int tx = t & 31, ty = t >> 5;        // ty in [0,8)
    int b = (blk >> 9) & 7;
    int n2t = (blk & 63) * 32, ct = ((blk >> 6) & 7) * 32;
#pragma unroll
    for (int i = 0; i < 4; ++i) {
      int c = ct + ty + i * 8;
      tile[ty + i * 8][tx] = f2[((size_t)b * 256 + c) * 2048 + n2t + tx];
    }
    __syncthreads();
#pragma unroll
    for (int i = 0; i < 4; ++i) {
      int n2 = n2t + ty + i * 8;
      f2t[((size_t)b * 2048 + n2) * 256 + ct + tx] = f2b(tile[tx][ty + i * 8]);
    }
  } else if (blk < 4480) {               // w1: 256x384
    int id = (blk - 4096) * 256 + t;
    unsigned o = (unsigned)id / 384u;
    unsigned c = (unsigned)id % 384u;
    w1b[(c >> 5) * 8192 + o * 32 + (c & 31)] = f2b(w1[id]);
  } else if (blk < 4736) {               // w2: 256x256
    int j = (blk - 4480) * 256 + t;
    unsigned o = (unsigned)j >> 8;
    unsigned c = (unsigned)j & 255u;
    w2b[(c >> 5) * 8192 + o * 32 + (c & 31)] = f2b(w2[j]);
  } else if (blk == 4736) {
    float a = g1[t] / sqrtf(v1[t] + BN_EPS);
    al1[t] = a;
    bt1[t] = (b1[t] - m1[t]) * a + be1[t];
  } else if (blk == 4737) {
    float a = g2[t] / sqrtf(v2[t] + BN_EPS);
    al2[t] = a;
    bt2[t] = (b2[t] - m2[t]) * a + be2[t];
  } else if (blk < 4802) {               // c4 planar candidate streams
    int idx = (blk - 4738) * 256 + t;
    int b = idx >> 11, j = idx & 2047;
    float cx = xyz2[b * 6144 + j];
    float cy = xyz2[b * 6144 + 2048 + j];
    float cz = xyz2[b * 6144 + 4096 + j];
    float nsq = (cx * cx + cy * cy) + cz * cz;   // same expr as old phase 0
    c4[b * 8192 + j] = cx;
    c4[b * 8192 + 2048 + j] = cy;
    c4[b * 8192 + 4096 + j] = cz;
    c4[b * 8192 + 6144 + j] = nsq;
  } else {                               // f1 -> xb kt 8..11 blocked bf16
    int idx = blk - 4802;                // [0, 4096)
    int b = idx >> 9;
    int rest = idx & 511;
    int ct = (rest >> 7) * 32;           // channel tile (0,32,64,96)
    int nt = (rest & 127) * 64;          // n1 tile
#pragma unroll
    for (int i = 0; i < 8; ++i) {
      int c = (t >> 6) + i * 4;
      int n = t & 63;
      tile2[c * 65 + n] = f1[((size_t)(b * 128 + ct + c)) * 8192 + nt + n];
    }
    __syncthreads();
    size_t base = (size_t)(b * 128 + (nt >> 6)) * 24576 + (size_t)(8 + (ct >> 5)) * 2048;
#pragma unroll
    for (int i = 0; i < 8; ++i) {
      int p = (t >> 5) + i * 8;
      int c = t & 31;
      xb[base + p * 32 + c] = f2b(tile2[c * 65 + p]);
    }
  }
}

// ---------------------------------------------------------------------------
// knn + interp. Candidate stream is WAVE-UNIFORM: read via uniform scalar
// loads from the c4 planar streams (s_load, lgkmcnt, scalar cache) instead
// of per-lane LDS broadcast reads — removes the per-candidate ds_read_b128
// and the 32 KB pts buffer (LDS now ~8.5 KB -> occupancy up).
// Comparator expression, sort network, slice merge order: identical to
// round-2/3 (selection bit-identical).
// ---------------------------------------------------------------------------
__global__ __launch_bounds__(256) void knn_interp_kernel(
    const float* __restrict__ xyz1, const float* __restrict__ c4,
    const u16* __restrict__ f2t, u16* __restrict__ xb) {
  __shared__ float md[256 * 3];          // 3072 B
  __shared__ int mi[256 * 3];            // 3072 B
  __shared__ float wts[64 * 3];
  __shared__ int idxs[64 * 3];           // premultiplied by 256

  int t = threadIdx.x;
  int b = blockIdx.x >> 7;
  int n1_0 = (blockIdx.x & 127) * 64;
  int panel = blockIdx.x;                // = b*128 + tile

  const float* x1 = xyz1 + b * 3 * 8192;

  // phase 1: sliced top-3; lane = query, wave = slice; candidates via s_load
  {
    int p = t & 63, s = t >> 6;
    int n1 = n1_0 + p;
    float bx = x1[n1], by = x1[8192 + n1], bz = x1[16384 + n1];
    float nx = -2.f * bx, ny = -2.f * by, nz = -2.f * bz;
    const float* cxp = c4 + b * 8192;
    const float* cyp = cxp + 2048;
    const float* czp = cxp + 4096;
    const float* cwp = cxp + 6144;
    // comparator value: sq' = |c|^2 - 2 q.c  (biased by -|q|^2, rank-equal)
    float d0 = 3.4e38f, d1 = 3.4e38f, d2 = 3.4e38f;
    int i0 = 0, i1 = 0, i2 = 0;
    int jb = s * 512;
#pragma unroll 8
    for (int jj = 0; jj < 512; ++jj) {
      int j = jb + jj;
      float sq = fmaf(nx, cxp[j], fmaf(ny, cyp[j], fmaf(nz, czp[j], cwp[j])));
      bool c0 = sq < d0, c1 = sq < d1, c2 = sq < d2;
      i2 = c1 ? i1 : (c2 ? j : i2);
      i1 = c0 ? i0 : (c1 ? j : i1);
      i0 = c0 ? j : i0;
      // sorted-invariant distance update (uses OLD d0/d1/d2)
      d2 = __builtin_amdgcn_fmed3f(sq, d1, d2);
      d1 = __builtin_amdgcn_fmed3f(sq, d0, d1);
      d0 = fminf(sq, d0);
    }
    md[t * 3 + 0] = d0; md[t * 3 + 1] = d1; md[t * 3 + 2] = d2;
    mi[t * 3 + 0] = i0; mi[t * 3 + 1] = i1; mi[t * 3 + 2] = i2;
  }
  __syncthreads();
  if (t < 64) {
    // merge slices s=0..3 in ascending-index order (preserves tie-break)
    float d0 = 3.4e38f, d1 = 3.4e38f, d2 = 3.4e38f;
    int i0 = 0, i1 = 0, i2 = 0;
#pragma unroll
    for (int s = 0; s < 4; ++s) {
#pragma unroll
      for (int k = 0; k < 3; ++k) {
        float d = md[(s * 64 + t) * 3 + k];
        int i = mi[(s * 64 + t) * 3 + k];
        bool c0 = d < d0, c1 = d < d1, c2 = d < d2;
        i2 = c1 ? i1 : (c2 ? i : i2);
        i1 = c0 ? i0 : (c1 ? i : i1);
        i0 = c0 ? i : i0;
        d2 = c1 ? d1 : (c2 ? d : d2);
        d1 = c0 ? d0 : (c1 ? d : d1);
        d0 = c0 ? d : d0;
      }
    }
    // un-bias: recompute |q|^2 for this query (3 L1-hot loads, 64 threads)
    int n1 = n1_0 + t;
    float bx = x1[n1], by = x1[8192 + n1], bz = x1[16384 + n1];
    float nn = (bx * bx + by * by) + bz * bz;
    float e0 = fmaxf(d0 + nn, 1e-10f), e1 = fmaxf(d1 + nn, 1e-10f), e2 = fmaxf(d2 + nn, 1e-10f);
    float w0 = 1.0f / e0, w1 = 1.0f / e1, w2 = 1.0f / e2;
    float sm = (w0 + w1) + w2;
    wts[t * 3 + 0] = w0 / sm; wts[t * 3 + 1] = w1 / sm; wts[t * 3 + 2] = w2 / sm;
    idxs[t * 3 + 0] = i0 * 256; idxs[t * 3 + 1] = i1 * 256; idxs[t * 3 + 2] = i2 * 256;
  }
  __syncthreads();

  // phase 2: interp 256 channels as 128 channel-pairs x 2 queries per iter
  {
    const u16* f2tb = f2t + (size_t)b * 2048 * 256;
    int tc = t & 127;                    // channel pair: channels 2tc, 2tc+1
    int ph = t >> 7;                     // query parity (uniform per wave)
    int ce = (2 * tc) & 31;              // even channel offset in 32-block
    size_t xbase = (size_t)panel * 24576 + (size_t)(tc >> 4) * 2048 + ce;
#pragma unroll 4
    for (int p2 = 0; p2 < 32; ++p2) {
      int p = p2 * 2 + ph;
      int j0 = idxs[p * 3 + 0], j1 = idxs[p * 3 + 1], j2 = idxs[p * 3 + 2];
      float w0 = wts[p * 3 + 0], w1 = wts[p * 3 + 1], w2 = wts[p * 3 + 2];
      unsigned a0 = *(const unsigned*)&f2tb[j0 + 2 * tc];
      unsigned a1 = *(const unsigned*)&f2tb[j1 + 2 * tc];
      unsigned a2 = *(const unsigned*)&f2tb[j2 + 2 * tc];
      float vlo = (w0 * asf(a0 << 16) + w1 * asf(a1 << 16)) + w2 * asf(a2 << 16);
      float vhi = (w0 * asf(a0 & 0xffff0000u) + w1 * asf(a1 & 0xffff0000u))
                  + w2 * asf(a2 & 0xffff0000u);
      unsigned pk = (unsigned)f2b(vlo) | ((unsigned)f2b(vhi) << 16);
      *(unsigned*)&xb[xbase + (size_t)p * 32] = pk;
    }
  }
}

// ---------------------------------------------------------------------------
// FUSED 2-layer GEMM with explicit depth-1 register software pipeline.
// (exact round-2 version: uniform B from xb, 12 kt, stride 24576)
// ---------------------------------------------------------------------------
__global__ __launch_bounds__(256) void gemm_fused_kernel(
    const u16* __restrict__ xin, const u16* __restrict__ w1b,
    const u16* __restrict__ w2b,
    const float* __restrict__ al1, const float* __restrict__ bt1,
    const float* __restrict__ al2, const float* __restrict__ bt2,
    float* __restrict__ fout) {
  __shared__ u16 y1t[8 * 64 * 40];       // 40960 B
  int t = threadIdx.x;
  int panel = blockIdx.x;
  int w = t >> 6, lane = t & 63, l15 = lane & 15, quad = lane >> 4;

  f32x4 acc[4][4];
#pragma unroll
  for (int m = 0; m < 4; ++m)
#pragma unroll
    for (int n = 0; n < 4; ++n)
      acc[m][n] = (f32x4){0.f, 0.f, 0.f, 0.f};

  // ---- layer 1 K-loop (KT=12), depth-1 register pipeline ----
  {
    const u16* aw = w1b + (size_t)(w * 64 + l15) * 32 + quad * 8;
    const u16* bx = xin + (size_t)panel * 24576 + (size_t)l15 * 32 + quad * 8;
    short8 af[2][4], bf[2][4];
#pragma unroll
    for (int m = 0; m < 4; ++m)
      af[0][m] = *(const short8*)(aw + m * 512);
#pragma unroll
    for (int n = 0; n < 4; ++n)
      bf[0][n] = *(const short8*)(bx + n * 512);
#pragma unroll
    for (int kt = 0; kt < 12; ++kt) {
      int cur = kt & 1, nxt = cur ^ 1;
      if (kt < 11) {
#pragma unroll
        for (int m = 0; m < 4; ++m)
          af[nxt][m] = *(const short8*)(aw + (kt + 1) * 8192 + m * 512);
#pragma unroll
        for (int n = 0; n < 4; ++n)
          bf[nxt][n] = *(const short8*)(bx + (kt + 1) * 2048 + n * 512);
      }
#pragma unroll
      for (int m = 0; m < 4; ++m)
#pragma unroll
        for (int n = 0; n < 4; ++n)
          acc[m][n] = __builtin_amdgcn_mfma_f32_16x16x32_bf16(af[cur][m], bf[cur][n], acc[m][n], 0, 0, 0);
    }
  }

  // ---- epilogue 1: BN+ReLU -> bf16 -> LDS y1 tile (blocked, stride 40) ----
  {
    float al[4][4], bt[4][4];
#pragma unroll
    for (int m = 0; m < 4; ++m)
#pragma unroll
      for (int r = 0; r < 4; ++r) {
        int o = w * 64 + m * 16 + quad * 4 + r;
        al[m][r] = al1[o];
        bt[m][r] = bt1[o];
      }
#pragma unroll
    for (int m = 0; m < 4; ++m) {
      int kt2 = w * 2 + (m >> 1);
      int osub = (m & 1) * 16 + quad * 4;
#pragma unroll
      for (int n = 0; n < 4; ++n) {
        int col = n * 16 + l15;
        ushort4 pk;
        pk.x = f2b(fmaxf(fmaf(al[m][0], acc[m][n][0], bt[m][0]), 0.f));
        pk.y = f2b(fmaxf(fmaf(al[m][1], acc[m][n][1], bt[m][1]), 0.f));
        pk.z = f2b(fmaxf(fmaf(al[m][2], acc[m][n][2], bt[m][2]), 0.f));
        pk.w = f2b(fmaxf(fmaf(al[m][3], acc[m][n][3], bt[m][3]), 0.f));
        *(ushort4*)&y1t[(kt2 * 64 + col) * 40 + osub] = pk;
      }
    }
  }
  __syncthreads();

  // ---- layer 2 K-loop (KT=8): A global (depth-1 pipeline), B from LDS ----
#pragma unroll
  for (int m = 0; m < 4; ++m)
#pragma unroll
    for (int n = 0; n < 4; ++n)
      acc[m][n] = (f32x4){0.f, 0.f, 0.f, 0.f};
  {
    const u16* aw = w2b + (size_t)(w * 64 + l15) * 32 + quad * 8;
    short8 af[2][4];
#pragma unroll
    for (int m = 0; m < 4; ++m)
      af[0][m] = *(const short8*)(aw + m * 512);
#pragma unroll
    for (int kt = 0; kt < 8; ++kt) {
      int cur = kt & 1, nxt = cur ^ 1;
      if (kt < 7) {
#pragma unroll
        for (int m = 0; m < 4; ++m)
          af[nxt][m] = *(const short8*)(aw + (kt + 1) * 8192 + m * 512);
      }
      short8 bf[4];
#pragma unroll
      for (int n = 0; n < 4; ++n)
        bf[n] = *(const short8*)&y1t[(kt * 64 + n * 16 + l15) * 40 + quad * 8];
#pragma unroll
      for (int m = 0; m < 4; ++m)
#pragma unroll
        for (int n = 0; n < 4; ++n)
          acc[m][n] = __builtin_amdgcn_mfma_f32_16x16x32_bf16(af[cur][m], bf[n], acc[m][n], 0, 0, 0);
    }
  }

  // ---- epilogue 2: BN+ReLU -> f32 out [b][256][8192] ----
  {
    float al[4][4], bt[4][4];
#pragma unroll
    for (int m = 0; m < 4; ++m)
#pragma unroll
      for (int r = 0; r < 4; ++r) {
        int o = w * 64 + m * 16 + quad * 4 + r;
        al[m][r] = al2[o];
        bt[m][r] = bt2[o];
      }
    int bb = panel >> 7;
    int n1base = (panel & 127) * 64;
#pragma unroll
    for (int m = 0; m < 4; ++m)
#pragma unroll
      for (int n = 0; n < 4; ++n) {
        int col = n * 16 + l15;
#pragma unroll
        for (int r = 0; r < 4; ++r) {
          int o = w * 64 + m * 16 + quad * 4 + r;
          float vv = fmaxf(fmaf(al[m][r], acc[m][n][r], bt[m][r]), 0.f);
          fout[(size_t)(bb * 256 + o) * 8192 + n1base + col] = vv;
        }
      }
  }
}

// ---------------------------------------------------------------------------
// ws layout (bytes):
//   [0,          50331648)  xb   bf16 [1024 panels][12][64][32]   48 MB
//                           (kt 0..7 by knn, kt 8..11 by prep from f1)
//   [50331648,   58720256)  f2t  bf16 [8][2048][256]               8 MB
//   [58720256,   58982400)  c4   f32  [8][4][2048] planar        256 KB
//   [83886080,   84082688)  w1b  bf16 blocked
//   [84082688,   84213760)  w2b  bf16 blocked
//   [84213760,   84217856)  al1/bt1/al2/bt2 f32
// ---------------------------------------------------------------------------
extern "C" void kernel_launch(void* const* d_in, const int* in_sizes, int n_in,
                              void* d_out, int out_size, void* d_ws, size_t ws_size,
                              hipStream_t stream) {
  const float* xyz1 = (const float*)d_in[0];
  const float* xyz2 = (const float*)d_in[1];
  const float* f1   = (const float*)d_in[2];
  const float* f2   = (const float*)d_in[3];
  const float* w1   = (const float*)d_in[4];
  const float* b1   = (const float*)d_in[5];
  const float* g1   = (const float*)d_in[6];
  const float* be1  = (const float*)d_in[7];
  const float* m1   = (const float*)d_in[8];
  const float* v1   = (const float*)d_in[9];
  const float* w2   = (const float*)d_in[10];
  const float* b2   = (const float*)d_in[11];
  const float* g2   = (const float*)d_in[12];
  const float* be2  = (const float*)d_in[13];
  const float* m2   = (const float*)d_in[14];
  const float* v2   = (const float*)d_in[15];

  char* ws = (char*)d_ws;
  u16* xb   = (u16*)(ws);
  u16* f2t  = (u16*)(ws + 50331648);
  float* c4 = (float*)(ws + 58720256);
  u16* w1b  = (u16*)(ws + 83886080);
  u16* w2b  = (u16*)(ws + 84082688);
  float* al1 = (float*)(ws + 84213760);
  float* bt1 = (float*)(ws + 84214784);
  float* al2 = (float*)(ws + 84215808);
  float* bt2 = (float*)(ws + 84216832);
  float* out = (float*)d_out;

  prep_kernel<<<8898, 256, 0, stream>>>(
      f2, f2t, w1, b1, g1, be1, m1, v1, w2, b2, g2, be2, m2, v2,
      xyz2, f1, w1b, w2b, al1, bt1, al2, bt2, c4, xb);
  knn_interp_kernel<<<1024, 256, 0, stream>>>(xyz1, c4, f2t, xb);
  gemm_fused_kernel<<<1024, 256, 0, stream>>>(xb, w1b, w2b, al1, bt1, al2, bt2, out);
}

// Round 5
// 217.396 us; speedup vs baseline: 1.1213x; 1.1213x over previous
//
#include <hip/hip_runtime.h>
#include <hip/hip_bf16.h>

typedef unsigned short u16;
typedef __attribute__((ext_vector_type(4))) float f32x4;
typedef __attribute__((ext_vector_type(8))) short short8;

#define BN_EPS 1e-5f

__device__ __forceinline__ u16 f2b(float x) {
  union { float f; unsigned int u; } v; v.f = x;
  unsigned int r = (v.u + 0x7FFFu + ((v.u >> 16) & 1u)) >> 16;
  return (u16)r;
}
__device__ __forceinline__ float b2f(u16 u) {
  union { unsigned int u; float f; } v; v.u = ((unsigned int)u) << 16;
  return v.f;
}
__device__ __forceinline__ float asf(unsigned u) {
  union { unsigned u; float f; } v; v.u = u; return v.f;
}

// ---------------------------------------------------------------------------
// prep + transpose fused (round-2 proven version).
// blk < 4096: transpose features2 [B][256][2048] f32 -> f2t [B][2048][256] bf16
// blk >= 4096: fold BN into alpha/beta; W1/W2 -> bf16 blocked [kt][o][32k]
// ---------------------------------------------------------------------------
__global__ void prep_transpose_kernel(
    const float* __restrict__ f2, u16* __restrict__ f2t,
    const float* __restrict__ w1, const float* __restrict__ b1,
    const float* __restrict__ g1, const float* __restrict__ be1,
    const float* __restrict__ m1, const float* __restrict__ v1,
    const float* __restrict__ w2, const float* __restrict__ b2,
    const float* __restrict__ g2, const float* __restrict__ be2,
    const float* __restrict__ m2, const float* __restrict__ v2,
    u16* __restrict__ w1b, u16* __restrict__ w2b,
    float* __restrict__ al1, float* __restrict__ bt1,
    float* __restrict__ al2, float* __restrict__ bt2) {
  __shared__ float tile[32][33];
  int t = threadIdx.x;
  int blk = blockIdx.x;
  if (blk < 4096) {
    int tx = t & 31, ty = t >> 5;        // ty in [0,8)
    int b = (blk >> 9) & 7;
    int n2t = (blk & 63) * 32, ct = ((blk >> 6) & 7) * 32;
#pragma unroll
    for (int i = 0; i < 4; ++i) {
      int c = ct + ty + i * 8;
      tile[ty + i * 8][tx] = f2[((size_t)b * 256 + c) * 2048 + n2t + tx];
    }
    __syncthreads();
#pragma unroll
    for (int i = 0; i < 4; ++i) {
      int n2 = n2t + ty + i * 8;
      f2t[((size_t)b * 2048 + n2) * 256 + ct + tx] = f2b(tile[tx][ty + i * 8]);
    }
  } else if (blk < 4480) {               // w1: 256x384
    int id = (blk - 4096) * 256 + t;
    unsigned o = (unsigned)id / 384u;
    unsigned c = (unsigned)id % 384u;
    w1b[(c >> 5) * 8192 + o * 32 + (c & 31)] = f2b(w1[id]);
  } else if (blk < 4736) {               // w2: 256x256
    int j = (blk - 4480) * 256 + t;
    unsigned o = (unsigned)j >> 8;
    unsigned c = (unsigned)j & 255u;
    w2b[(c >> 5) * 8192 + o * 32 + (c & 31)] = f2b(w2[j]);
  } else if (blk == 4736) {
    float a = g1[t] / sqrtf(v1[t] + BN_EPS);
    al1[t] = a;
    bt1[t] = (b1[t] - m1[t]) * a + be1[t];
  } else {
    float a = g2[t] / sqrtf(v2[t] + BN_EPS);
    al2[t] = a;
    bt2[t] = (b2[t] - m2[t]) * a + be2[t];
  }
}

// ---------------------------------------------------------------------------
// knn + interp + skip-copy — round-2 structure (4 waves/block, sliced scan,
// LDS-broadcast candidate reads) with a BRANCH-GATED insertion network:
// the 4 ds_read_b128 of an unroll group are issued BEFORE the 4 update
// blocks (loads unconditional -> latency batched, the R1 failure mode),
// and the ~10-op sort/index network only runs when __any lane improves
// (~26% of iterations at 512-long streams). Per-lane med3/min/cndmask are
// identity for non-improving lanes -> selection bit-identical to round 2.
// ---------------------------------------------------------------------------
__global__ __launch_bounds__(256) void knn_interp_kernel(
    const float* __restrict__ xyz1, const float* __restrict__ xyz2,
    const float* __restrict__ f1, const u16* __restrict__ f2t,
    u16* __restrict__ xb) {
  union Lds {
    struct { float4 pts[2048]; float md[256 * 3]; u16 mi[256 * 3]; } a;
    float f1t[128 * 65];
  };
  __shared__ Lds lds;
  __shared__ float wts[64 * 3];
  __shared__ int idxs[64 * 3];           // premultiplied by 256

  int t = threadIdx.x;
  int b = blockIdx.x >> 7;
  int n1_0 = (blockIdx.x & 127) * 64;
  int panel = blockIdx.x;                // = b*128 + tile

  // phase 0: stage candidates (x,y,z,|x|^2)
  const float* x2 = xyz2 + b * 3 * 2048;
  for (int j = t; j < 2048; j += 256) {
    float cx = x2[j], cy = x2[2048 + j], cz = x2[4096 + j];
    float nsq = (cx * cx + cy * cy) + cz * cz;
    lds.a.pts[j] = make_float4(cx, cy, cz, nsq);
  }
  __syncthreads();

  const float* x1 = xyz1 + b * 3 * 8192;

  // phase 1: sliced top-3; lane = query, wave = slice (broadcast LDS reads)
  {
    int p = t & 63, s = t >> 6;
    int n1 = n1_0 + p;
    float bx = x1[n1], by = x1[8192 + n1], bz = x1[16384 + n1];
    float nx = -2.f * bx, ny = -2.f * by, nz = -2.f * bz;
    // comparator value: sq' = |c|^2 - 2 q.c  (biased by -|q|^2, rank-equal)
    float d0 = 3.4e38f, d1 = 3.4e38f, d2 = 3.4e38f;
    int i0 = 0, i1 = 0, i2 = 0;
    int jb = s * 512;

#define KNN_UPD(cv, jv)                                                      \
    {                                                                        \
      float sq = fmaf(nx, (cv).x, fmaf(ny, (cv).y, fmaf(nz, (cv).z, (cv).w))); \
      if (__any(sq < d2)) {                                                  \
        bool c0 = sq < d0, c1 = sq < d1, c2 = sq < d2;                       \
        i2 = c1 ? i1 : (c2 ? (jv) : i2);                                     \
        i1 = c0 ? i0 : (c1 ? (jv) : i1);                                     \
        i0 = c0 ? (jv) : i0;                                                 \
        d2 = __builtin_amdgcn_fmed3f(sq, d1, d2);                            \
        d1 = __builtin_amdgcn_fmed3f(sq, d0, d1);                            \
        d0 = fminf(sq, d0);                                                  \
      }                                                                      \
    }

    for (int jj = 0; jj < 512; jj += 4) {
      float4 ca = lds.a.pts[jb + jj + 0];
      float4 cb = lds.a.pts[jb + jj + 1];
      float4 cc = lds.a.pts[jb + jj + 2];
      float4 cd = lds.a.pts[jb + jj + 3];
      KNN_UPD(ca, jb + jj + 0);
      KNN_UPD(cb, jb + jj + 1);
      KNN_UPD(cc, jb + jj + 2);
      KNN_UPD(cd, jb + jj + 3);
    }
#undef KNN_UPD
    lds.a.md[t * 3 + 0] = d0; lds.a.md[t * 3 + 1] = d1; lds.a.md[t * 3 + 2] = d2;
    lds.a.mi[t * 3 + 0] = (u16)i0; lds.a.mi[t * 3 + 1] = (u16)i1; lds.a.mi[t * 3 + 2] = (u16)i2;
  }
  __syncthreads();
  if (t < 64) {
    // merge slices s=0..3 in ascending-index order (preserves tie-break)
    float d0 = 3.4e38f, d1 = 3.4e38f, d2 = 3.4e38f;
    int i0 = 0, i1 = 0, i2 = 0;
#pragma unroll
    for (int s = 0; s < 4; ++s) {
#pragma unroll
      for (int k = 0; k < 3; ++k) {
        float d = lds.a.md[(s * 64 + t) * 3 + k];
        int i = (int)lds.a.mi[(s * 64 + t) * 3 + k];
        bool c0 = d < d0, c1 = d < d1, c2 = d < d2;
        i2 = c1 ? i1 : (c2 ? i : i2);
        i1 = c0 ? i0 : (c1 ? i : i1);
        i0 = c0 ? i : i0;
        d2 = c1 ? d1 : (c2 ? d : d2);
        d1 = c0 ? d0 : (c1 ? d : d1);
        d0 = c0 ? d : d0;
      }
    }
    // un-bias: recompute |q|^2 for this query (3 L1-hot loads, 64 threads)
    int n1 = n1_0 + t;
    float bx = x1[n1], by = x1[8192 + n1], bz = x1[16384 + n1];
    float nn = (bx * bx + by * by) + bz * bz;
    float e0 = fmaxf(d0 + nn, 1e-10f), e1 = fmaxf(d1 + nn, 1e-10f), e2 = fmaxf(d2 + nn, 1e-10f);
    float w0 = 1.0f / e0, w1 = 1.0f / e1, w2 = 1.0f / e2;
    float sm = (w0 + w1) + w2;
    wts[t * 3 + 0] = w0 / sm; wts[t * 3 + 1] = w1 / sm; wts[t * 3 + 2] = w2 / sm;
    idxs[t * 3 + 0] = i0 * 256; idxs[t * 3 + 1] = i1 * 256; idxs[t * 3 + 2] = i2 * 256;
  }
  __syncthreads();

  // phase 2: interp 256 channels as 64 channel-quads x 4 query groups
  // (uint2 gathers: half the loads/stores/iterations of the pair version;
  //  per-channel arithmetic expression identical)
  {
    const u16* f2tb = f2t + (size_t)b * 2048 * 256;
    int tc = t & 63;                     // channel quad: channels 4tc..4tc+3
    int qg = t >> 6;                     // query group (uniform per wave)
    int ce = (4 * tc) & 31;              // channel offset within 32-block
    size_t xbase = (size_t)panel * 24576 + (size_t)(tc >> 3) * 2048 + ce;
#pragma unroll 4
    for (int p2 = 0; p2 < 16; ++p2) {
      int p = p2 * 4 + qg;
      int j0 = idxs[p * 3 + 0], j1 = idxs[p * 3 + 1], j2 = idxs[p * 3 + 2];
      float w0 = wts[p * 3 + 0], w1 = wts[p * 3 + 1], w2 = wts[p * 3 + 2];
      uint2 a0 = *(const uint2*)&f2tb[j0 + 4 * tc];
      uint2 a1 = *(const uint2*)&f2tb[j1 + 4 * tc];
      uint2 a2 = *(const uint2*)&f2tb[j2 + 4 * tc];
      float v0 = (w0 * asf(a0.x << 16) + w1 * asf(a1.x << 16)) + w2 * asf(a2.x << 16);
      float v1 = (w0 * asf(a0.x & 0xffff0000u) + w1 * asf(a1.x & 0xffff0000u))
                 + w2 * asf(a2.x & 0xffff0000u);
      float v2 = (w0 * asf(a0.y << 16) + w1 * asf(a1.y << 16)) + w2 * asf(a2.y << 16);
      float v3 = (w0 * asf(a0.y & 0xffff0000u) + w1 * asf(a1.y & 0xffff0000u))
                 + w2 * asf(a2.y & 0xffff0000u);
      uint2 pk;
      pk.x = (unsigned)f2b(v0) | ((unsigned)f2b(v1) << 16);
      pk.y = (unsigned)f2b(v2) | ((unsigned)f2b(v3) << 16);
      *(uint2*)&xb[xbase + (size_t)p * 32] = pk;
    }
  }
  __syncthreads();   // before aliasing lds.a with lds.f1t

  // phase 3: skip features (channels 256..383) via LDS transpose
  {
    const float* f1b = f1 + (size_t)b * 128 * 8192 + n1_0;
    for (int it = 0; it < 32; ++it) {
      int c = it * 4 + (t >> 6);
      int n = t & 63;
      lds.f1t[c * 65 + n] = f1b[(size_t)c * 8192 + n];
    }
    __syncthreads();
    for (int it = 0; it < 32; ++it) {
      int v = it * 256 + t;
      int c = v & 127, p = v >> 7;
      float val = lds.f1t[c * 65 + p];
      xb[(size_t)panel * 24576 + (size_t)(8 + (c >> 5)) * 2048 + p * 32 + (c & 31)] = f2b(val);
    }
  }
}

// ---------------------------------------------------------------------------
// FUSED 2-layer GEMM with explicit depth-1 register software pipeline.
// (unchanged round-2 version)
// ---------------------------------------------------------------------------
__global__ __launch_bounds__(256) void gemm_fused_kernel(
    const u16* __restrict__ xin, const u16* __restrict__ w1b,
    const u16* __restrict__ w2b,
    const float* __restrict__ al1, const float* __restrict__ bt1,
    const float* __restrict__ al2, const float* __restrict__ bt2,
    float* __restrict__ fout) {
  __shared__ u16 y1t[8 * 64 * 40];       // 40960 B
  int t = threadIdx.x;
  int panel = blockIdx.x;
  int w = t >> 6, lane = t & 63, l15 = lane & 15, quad = lane >> 4;

  f32x4 acc[4][4];
#pragma unroll
  for (int m = 0; m < 4; ++m)
#pragma unroll
    for (int n = 0; n < 4; ++n)
      acc[m][n] = (f32x4){0.f, 0.f, 0.f, 0.f};

  // ---- layer 1 K-loop (KT=12), depth-1 register pipeline ----
  {
    const u16* aw = w1b + (size_t)(w * 64 + l15) * 32 + quad * 8;
    const u16* bx = xin + (size_t)panel * 24576 + (size_t)l15 * 32 + quad * 8;
    short8 af[2][4], bf[2][4];
#pragma unroll
    for (int m = 0; m < 4; ++m)
      af[0][m] = *(const short8*)(aw + m * 512);
#pragma unroll
    for (int n = 0; n < 4; ++n)
      bf[0][n] = *(const short8*)(bx + n * 512);
#pragma unroll
    for (int kt = 0; kt < 12; ++kt) {
      int cur = kt & 1, nxt = cur ^ 1;
      if (kt < 11) {
#pragma unroll
        for (int m = 0; m < 4; ++m)
          af[nxt][m] = *(const short8*)(aw + (kt + 1) * 8192 + m * 512);
#pragma unroll
        for (int n = 0; n < 4; ++n)
          bf[nxt][n] = *(const short8*)(bx + (kt + 1) * 2048 + n * 512);
      }
#pragma unroll
      for (int m = 0; m < 4; ++m)
#pragma unroll
        for (int n = 0; n < 4; ++n)
          acc[m][n] = __builtin_amdgcn_mfma_f32_16x16x32_bf16(af[cur][m], bf[cur][n], acc[m][n], 0, 0, 0);
    }
  }

  // ---- epilogue 1: BN+ReLU -> bf16 -> LDS y1 tile (blocked, stride 40) ----
  {
    float al[4][4], bt[4][4];
#pragma unroll
    for (int m = 0; m < 4; ++m)
#pragma unroll
      for (int r = 0; r < 4; ++r) {
        int o = w * 64 + m * 16 + quad * 4 + r;
        al[m][r] = al1[o];
        bt[m][r] = bt1[o];
      }
#pragma unroll
    for (int m = 0; m < 4; ++m) {
      int kt2 = w * 2 + (m >> 1);
      int osub = (m & 1) * 16 + quad * 4;
#pragma unroll
      for (int n = 0; n < 4; ++n) {
        int col = n * 16 + l15;
        ushort4 pk;
        pk.x = f2b(fmaxf(fmaf(al[m][0], acc[m][n][0], bt[m][0]), 0.f));
        pk.y = f2b(fmaxf(fmaf(al[m][1], acc[m][n][1], bt[m][1]), 0.f));
        pk.z = f2b(fmaxf(fmaf(al[m][2], acc[m][n][2], bt[m][2]), 0.f));
        pk.w = f2b(fmaxf(fmaf(al[m][3], acc[m][n][3], bt[m][3]), 0.f));
        *(ushort4*)&y1t[(kt2 * 64 + col) * 40 + osub] = pk;
      }
    }
  }
  __syncthreads();

  // ---- layer 2 K-loop (KT=8): A global (depth-1 pipeline), B from LDS ----
#pragma unroll
  for (int m = 0; m < 4; ++m)
#pragma unroll
    for (int n = 0; n < 4; ++n)
      acc[m][n] = (f32x4){0.f, 0.f, 0.f, 0.f};
  {
    const u16* aw = w2b + (size_t)(w * 64 + l15) * 32 + quad * 8;
    short8 af[2][4];
#pragma unroll
    for (int m = 0; m < 4; ++m)
      af[0][m] = *(const short8*)(aw + m * 512);
#pragma unroll
    for (int kt = 0; kt < 8; ++kt) {
      int cur = kt & 1, nxt = cur ^ 1;
      if (kt < 7) {
#pragma unroll
        for (int m = 0; m < 4; ++m)
          af[nxt][m] = *(const short8*)(aw + (kt + 1) * 8192 + m * 512);
      }
      short8 bf[4];
#pragma unroll
      for (int n = 0; n < 4; ++n)
        bf[n] = *(const short8*)&y1t[(kt * 64 + n * 16 + l15) * 40 + quad * 8];
#pragma unroll
      for (int m = 0; m < 4; ++m)
#pragma unroll
        for (int n = 0; n < 4; ++n)
          acc[m][n] = __builtin_amdgcn_mfma_f32_16x16x32_bf16(af[cur][m], bf[n], acc[m][n], 0, 0, 0);
    }
  }

  // ---- epilogue 2: BN+ReLU -> f32 out [b][256][8192] ----
  {
    float al[4][4], bt[4][4];
#pragma unroll
    for (int m = 0; m < 4; ++m)
#pragma unroll
      for (int r = 0; r < 4; ++r) {
        int o = w * 64 + m * 16 + quad * 4 + r;
        al[m][r] = al2[o];
        bt[m][r] = bt2[o];
      }
    int bb = panel >> 7;
    int n1base = (panel & 127) * 64;
#pragma unroll
    for (int m = 0; m < 4; ++m)
#pragma unroll
      for (int n = 0; n < 4; ++n) {
        int col = n * 16 + l15;
#pragma unroll
        for (int r = 0; r < 4; ++r) {
          int o = w * 64 + m * 16 + quad * 4 + r;
          float vv = fmaxf(fmaf(al[m][r], acc[m][n][r], bt[m][r]), 0.f);
          fout[(size_t)(bb * 256 + o) * 8192 + n1base + col] = vv;
        }
      }
  }
}

// ---------------------------------------------------------------------------
// ws layout (bytes):
//   [0,          50331648)  xb   bf16 [1024 panels][12][64][32]   48 MB
//   [50331648,   58720256)  f2t  bf16 [8][2048][256]               8 MB
//   [83886080,   84082688)  w1b  bf16 blocked
//   [84082688,   84213760)  w2b  bf16 blocked
//   [84213760,   84217856)  al1/bt1/al2/bt2 f32
// ---------------------------------------------------------------------------
extern "C" void kernel_launch(void* const* d_in, const int* in_sizes, int n_in,
                              void* d_out, int out_size, void* d_ws, size_t ws_size,
                              hipStream_t stream) {
  const float* xyz1 = (const float*)d_in[0];
  const float* xyz2 = (const float*)d_in[1];
  const float* f1   = (const float*)d_in[2];
  const float* f2   = (const float*)d_in[3];
  const float* w1   = (const float*)d_in[4];
  const float* b1   = (const float*)d_in[5];
  const float* g1   = (const float*)d_in[6];
  const float* be1  = (const float*)d_in[7];
  const float* m1   = (const float*)d_in[8];
  const float* v1   = (const float*)d_in[9];
  const float* w2   = (const float*)d_in[10];
  const float* b2   = (const float*)d_in[11];
  const float* g2   = (const float*)d_in[12];
  const float* be2  = (const float*)d_in[13];
  const float* m2   = (const float*)d_in[14];
  const float* v2   = (const float*)d_in[15];

  char* ws = (char*)d_ws;
  u16* xb   = (u16*)(ws);
  u16* f2t  = (u16*)(ws + 50331648);
  u16* w1b  = (u16*)(ws + 83886080);
  u16* w2b  = (u16*)(ws + 84082688);
  float* al1 = (float*)(ws + 84213760);
  float* bt1 = (float*)(ws + 84214784);
  float* al2 = (float*)(ws + 84215808);
  float* bt2 = (float*)(ws + 84216832);
  float* out = (float*)d_out;

  prep_transpose_kernel<<<4738, 256, 0, stream>>>(
      f2, f2t, w1, b1, g1, be1, m1, v1, w2, b2, g2, be2, m2, v2,
      w1b, w2b, al1, bt1, al2, bt2);
  knn_interp_kernel<<<1024, 256, 0, stream>>>(xyz1, xyz2, f1, f2t, xb);
  gemm_fused_kernel<<<1024, 256, 0, stream>>>(xb, w1b, w2b, al1, bt1, al2, bt2, out);
}